// Round 18
// baseline (342.540 us; speedup 1.0000x reference)
//
// r44: colscan 4-way chunk-split. csrg's colscan leg ran on 49 blocks (19%
// of CUs) serially walking 128 chunks; now 196 blocks each scan a 32-chunk
// group locally (lanes stay on contiguous w — r36 lesson), packed subtotals
// S[4][12544]; tiny k_cscanb makes exclusive group offsets (byte adds, all
// sums <255 => exact), emits deg+bsum. fill3 adds one L2-hot S load:
// base = G[b][w] + S[b/32][w]. +1 launch. All integer-exact.
#include <hip/hip_runtime.h>
#include <hip/hip_fp16.h>
#include <stdio.h>

struct __align__(8) Half4 { __half2 a, b; };
struct __align__(16) H8 { __half h[8]; };

typedef _Float16 f16x8 __attribute__((ext_vector_type(8)));
typedef float f32x4 __attribute__((ext_vector_type(4)));

#define CSR_NB 128       // chunks along edge dim
#define CSR_NW1 12544    // LDS words, full node range (4 nodes/word, 50176B)
#define CSR_WROW8 12544  // words per G row
#define CGRP 4           // colscan chunk groups
#define CHPG 32          // chunks per group = CSR_NB/CGRP
#define CSCAN_NB2 196    // 4 groups x 49 w-blocks

// acc += (fp16 half of word) * p, fp32 accumulate (exact fp16->fp32 convert)
#define FMIX_LO(acc, word, p)                                              \
  asm("v_fma_mix_f32 %0, %1, %2, %0 op_sel:[0,0,0] op_sel_hi:[1,0,0]"      \
      : "+v"(acc) : "v"(word), "v"(p))
#define FMIX_HI(acc, word, p)                                              \
  asm("v_fma_mix_f32 %0, %1, %2, %0 op_sel:[1,0,0] op_sel_hi:[1,0,0]"      \
      : "+v"(acc) : "v"(word), "v"(p))

__device__ __forceinline__ unsigned int f2key(float f) {
  unsigned int u = __float_as_uint(f);
  return (u & 0x80000000u) ? ~u : (u | 0x80000000u);
}
__device__ __forceinline__ float key2f(unsigned int k) {
  return __uint_as_float((k & 0x80000000u) ? (k ^ 0x80000000u) : ~k);
}
// swizzled byte offset of element (col, k) in the 32KB B^T LDS image
__device__ __forceinline__ int bswz(int col, int k) {
  return ((col << 8) + (k << 1)) ^ ((col & 7) << 4);
}

// MFMA 128x128 gemm body; BH = pre-swizzled fp16 B^T image (32KB).
__device__ __forceinline__ void gemm_body(
    const __half* Ah, const __half* BH, const float* bias, float* out, int N,
    int relu, const float* att_s, const float* att_d, float* asb, float* adb,
    unsigned int* mkey, const float* encx, const float* encw,
    const float* encb, const float* ew2, const float* eb2, const float* rw2,
    const float* rb2, float* hout, int blk) {
  __shared__ char sbuf[49152] __attribute__((aligned(16)));
  __shared__ __half Wh[1024];
  __shared__ float Wb[128];
  __shared__ unsigned int smax[4];
  char* Btb = sbuf + 16384;
  float* Cs = (float*)sbuf;
  const int t = threadIdx.x, tx = t & 31, ty = t >> 5;
  const int l = t & 63, wv = t >> 6;
  const int row0 = blk * 64;
  if (t < 4) smax[t] = 0u;
  if (encx) {
    for (int i = t; i < 1024; i += 256) Wh[i] = __float2half(encw[i]);
    if (t < 128) Wb[t] = encb[t];
  }
  __syncthreads();
  // ---- stage B^T: straight 16B copies of the pre-swizzled image ----
  {
    const uint4* bh4 = (const uint4*)BH;
    uint4* bt4 = (uint4*)Btb;
    for (int idx = t; idx < 2048; idx += 256) bt4[idx] = bh4[idx];
  }
  if (encx) {
    for (int idx = t; idx < 1024; idx += 256) {
      int r = idx >> 4, u8 = idx & 15, row = row0 + r;
      H8 hv;
      if (row < N) {
        float xv[8];
        *(float4*)(xv) = *(const float4*)(encx + (size_t)row * 8);
        *(float4*)(xv + 4) = *(const float4*)(encx + (size_t)row * 8 + 4);
#pragma unroll
        for (int j = 0; j < 8; ++j) {
          int c = u8 * 8 + j;
          float a = Wb[c];
#pragma unroll
          for (int k = 0; k < 8; ++k)
            a += xv[k] * __half2float(Wh[k * 128 + c]);
          hv.h[j] = __float2half(fmaxf(a, 0.f));
        }
      } else {
#pragma unroll
        for (int j = 0; j < 8; ++j) hv.h[j] = __float2half(0.f);
      }
      int byte = ((r << 8) + (u8 << 4)) ^ ((r & 7) << 4);
      *(H8*)(sbuf + byte) = hv;
    }
  } else {
    for (int idx = t; idx < 1024; idx += 256) {
      int r = idx >> 4, u8 = idx & 15, row = row0 + r;
      H8 hv;
      if (row < N) {
        hv = *(const H8*)(Ah + (size_t)row * 128 + u8 * 8);
      } else {
#pragma unroll
        for (int j = 0; j < 8; ++j) hv.h[j] = __float2half(0.f);
      }
      int byte = ((r << 8) + (u8 << 4)) ^ ((r & 7) << 4);
      *(H8*)(sbuf + byte) = hv;
    }
  }
  __syncthreads();
  f32x4 acc[8];
#pragma unroll
  for (int c = 0; c < 8; ++c) acc[c] = (f32x4){0.f, 0.f, 0.f, 0.f};
  {
    const int lr = l & 15, kb = (l >> 4) * 8;
    const int arow = wv * 16 + lr;
#pragma unroll
    for (int ks = 0; ks < 4; ++ks) {
      int ak = ks * 32 + kb;
      int abyte = ((arow << 8) + (ak << 1)) ^ ((arow & 7) << 4);
      f16x8 af = *(const f16x8*)(sbuf + abyte);
#pragma unroll
      for (int c = 0; c < 8; ++c) {
        int bcol = c * 16 + lr;
        f16x8 bf = *(const f16x8*)(Btb + bswz(bcol, ak));
        acc[c] = __builtin_amdgcn_mfma_f32_16x16x32_f16(af, bf, acc[c], 0, 0, 0);
      }
    }
  }
  __syncthreads();
  {
    const int lr = l & 15, lq = l >> 4;
#pragma unroll
    for (int c = 0; c < 8; ++c)
#pragma unroll
      for (int i = 0; i < 4; ++i)
        Cs[(wv * 16 + lq * 4 + i) * 128 + c * 16 + lr] = acc[c][i];
  }
  __syncthreads();
  float b0 = 0.f, b1 = 0.f, b2 = 0.f, b3 = 0.f;
  const int c0 = tx * 4;
  if (bias) { b0 = bias[c0]; b1 = bias[c0 + 1]; b2 = bias[c0 + 2]; b3 = bias[c0 + 3]; }
  float4 sv = make_float4(0.f, 0.f, 0.f, 0.f), dv = sv;
  if (att_s) {
    sv = *(const float4*)(att_s + c0);
    dv = *(const float4*)(att_d + c0);
  }
  unsigned int kmax = 0u;
#pragma unroll
  for (int i = 0; i < 8; ++i) {
    int row = row0 + ty * 8 + i;
    float4 cv = *(const float4*)(Cs + (ty * 8 + i) * 128 + c0);
    float4 o = make_float4(cv.x + b0, cv.y + b1, cv.z + b2, cv.w + b3);
    if (relu) {
      o.x = fmaxf(o.x, 0.f); o.y = fmaxf(o.y, 0.f);
      o.z = fmaxf(o.z, 0.f); o.w = fmaxf(o.w, 0.f);
    }
    if (att_s) {
      if (row < N) {
        Half4 hv;
        hv.a = __floats2half2_rn(o.x, o.y);
        hv.b = __floats2half2_rn(o.z, o.w);
        *(Half4*)((__half*)out + (size_t)row * 128 + c0) = hv;
      }
      float ps = o.x * sv.x + o.y * sv.y + o.z * sv.z + o.w * sv.w;
      float pd = o.x * dv.x + o.y * dv.y + o.z * dv.z + o.w * dv.w;
#pragma unroll
      for (int off = 4; off >= 1; off >>= 1) {
        ps += __shfl_xor(ps, off);
        pd += __shfl_xor(pd, off);
      }
      if ((tx & 7) == 0 && row < N) {
        int h = tx >> 3;
        asb[(size_t)row * 4 + h] = ps;
        adb[(size_t)row * 4 + h] = pd;
        unsigned int k = f2key(ps);
        kmax = kmax > k ? kmax : k;
      }
    } else if (hout) {
      float pa0 = 0.f, pa1 = 0.f, pa2 = 0.f, pa3 = 0.f, pr = 0.f;
      if (tx < 16) {
        const float* w0 = ew2 + (size_t)c0 * 4;
        pa0 = o.x * w0[0] + o.y * w0[4] + o.z * w0[8] + o.w * w0[12];
        pa1 = o.x * w0[1] + o.y * w0[5] + o.z * w0[9] + o.w * w0[13];
        pa2 = o.x * w0[2] + o.y * w0[6] + o.z * w0[10] + o.w * w0[14];
        pa3 = o.x * w0[3] + o.y * w0[7] + o.z * w0[11] + o.w * w0[15];
      } else {
        const float* wr = rw2 + (c0 - 64);
        pr = o.x * wr[0] + o.y * wr[1] + o.z * wr[2] + o.w * wr[3];
      }
#pragma unroll
      for (int off = 1; off <= 8; off <<= 1) {
        pa0 += __shfl_xor(pa0, off); pa1 += __shfl_xor(pa1, off);
        pa2 += __shfl_xor(pa2, off); pa3 += __shfl_xor(pa3, off);
        pr += __shfl_xor(pr, off);
      }
      if (row < N) {
        if (tx == 0) {
          hout[(size_t)row * 4 + 0] = pa0 + eb2[0];
          hout[(size_t)row * 4 + 1] = pa1 + eb2[1];
          hout[(size_t)row * 4 + 2] = pa2 + eb2[2];
          hout[(size_t)row * 4 + 3] = pa3 + eb2[3];
        }
        if (tx == 16) hout[(size_t)N * 4 + row] = pr + rb2[0];
      }
    } else if (row < N) {
      *(float4*)(out + (size_t)row * 128 + c0) = o;
    }
  }
  if (att_s) {
    if ((tx & 7) == 0 && kmax) atomicMax(&smax[tx >> 3], kmax);
    __syncthreads();
    if (t < 4) atomicMax(&mkey[t], smax[t]);
  }
}

// plain gemm wrapper (GAT2 + final)
__global__ void k_gemm128(const __half* Ah, const __half* BH,
                          const float* bias, float* out, int N, int relu,
                          const float* att_s, const float* att_d, float* asb,
                          float* adb, unsigned int* mkey, const float* ew2,
                          const float* eb2, const float* rw2,
                          const float* rb2, float* hout) {
  gemm_body(Ah, BH, bias, out, N, relu, att_s, att_d, asb, adb, mkey,
            (const float*)0, (const float*)0, (const float*)0, ew2, eb2, rw2,
            rb2, hout, blockIdx.x);
}

// hist (0..127, 1024 thr) + prep: WcH concat+mkey (128..143), wfold->WpH
// (144..159), g2_w->G2H convert (160..175).
__global__ void k_histp(const int* dst, unsigned int* G, unsigned char* rank8,
                        int E, int N, int chunk, const float* ew1,
                        const float* eb1, const float* rw1, const float* rb1,
                        __half* WcH, float* bc, unsigned int* mkey,
                        const float* w2, const float* b2, const float* gw,
                        __half* WpH, float* bp, const float* g2w,
                        __half* G2H) {
  __shared__ unsigned int hist[CSR_NW1];
  const int blk = blockIdx.x, t = threadIdx.x;
  if (blk < CSR_NB) {
    uint4* h4 = (uint4*)hist;
    uint4 z4 = make_uint4(0u, 0u, 0u, 0u);
    for (int i = t; i < CSR_NW1 / 4; i += 1024) h4[i] = z4;
    __syncthreads();
    const int e0 = blk * chunk, e1 = min(E, e0 + chunk);
    for (int e = e0 + t; e < e1; e += 1024) {
      int d = dst[e];
      if (d >= 0 && d < N) {
        int sh = (d & 3) * 8;
        unsigned int old = atomicAdd(&hist[(unsigned int)d >> 2], 1u << sh);
        rank8[e] = (unsigned char)((old >> sh) & 0xffu);
      }
    }
    __syncthreads();
    uint4* row4 = (uint4*)(G + (size_t)blk * CSR_WROW8);
    for (int i = t; i < CSR_NW1 / 4; i += 1024) row4[i] = h4[i];
  } else if (blk < CSR_NB + 16) {
    int i = (blk - CSR_NB) * 1024 + t;
    if (i < 4) mkey[i] = 0u;
    int k = i >> 7, m = i & 127;
    float v = (m < 64) ? ew1[k * 64 + m] : rw1[k * 64 + (m - 64)];
    *(__half*)((char*)WcH + bswz(m, k)) = __float2half(v);
    if (i < 128) bc[i] = (i < 64) ? eb1[i] : rb1[i - 64];
  } else if (blk < CSR_NB + 32) {
    int id = (blk - CSR_NB - 16) * 1024 + t;
    int k = id >> 7, m = id & 127;
    float s = 0.f;
    for (int j = 0; j < 128; ++j) s += w2[k * 128 + j] * gw[j * 128 + m];
    *(__half*)((char*)WpH + bswz(m, k)) = __float2half(s);
    if (id < 128) {
      float s2 = 0.f;
      for (int j = 0; j < 128; ++j) s2 += b2[j] * gw[j * 128 + id];
      bp[id] = s2;
    }
  } else {
    int id = (blk - CSR_NB - 32) * 1024 + t;
    int k = id >> 7, m = id & 127;
    *(__half*)((char*)G2H + bswz(m, k)) = __float2half(g2w[id]);
  }
}

// colscan-A (blocks 0..195: group g=blk/49 scans its 32 chunks locally,
// packed subtotal -> S[g][w]) CONCURRENT with GAT1 gemm (blocks 196..).
__global__ void k_csrg(unsigned int* G, unsigned int* S, int N,
                       const __half* BH, const float* bias, float* out,
                       const float* att_s, const float* att_d, float* asb,
                       float* adb, unsigned int* mkey, const float* encx,
                       const float* encw, const float* encb) {
  if (blockIdx.x < CSCAN_NB2) {
    int g = blockIdx.x / 49, wb = blockIdx.x % 49;
    int w = wb * 256 + threadIdx.x;
    if (w < CSR_WROW8) {
      unsigned int run = 0u;
      int b0 = g * CHPG, b1 = b0 + CHPG;
      for (int b = b0; b < b1; ++b) {
        size_t idx = (size_t)b * CSR_WROW8 + w;
        unsigned int c = G[idx];
        G[idx] = run;
        run += c;
      }
      S[(size_t)g * CSR_WROW8 + w] = run;
    }
  } else {
    gemm_body((const __half*)0, BH, bias, out, N, 0, att_s, att_d, asb, adb,
              mkey, encx, encw, encb, (const float*)0, (const float*)0,
              (const float*)0, (const float*)0, (float*)0,
              blockIdx.x - CSCAN_NB2);
  }
}

// colscan-B: exclusive group offsets (packed byte adds, exact: totals <255),
// emit deg + per-1024-node bsum. 49 blocks x 256 thr, block == scan3b tile.
__global__ void k_cscanb(unsigned int* S, int* deg, int* bsum, int N) {
  __shared__ int sh[256];
  int t = threadIdx.x, w = blockIdx.x * 256 + t;
  unsigned int tot = 0u;
  if (w < CSR_WROW8) {
    unsigned int u0 = S[w];
    unsigned int u1 = S[CSR_WROW8 + w];
    unsigned int u2 = S[2 * CSR_WROW8 + w];
    unsigned int u3 = S[3 * CSR_WROW8 + w];
    S[w] = 0u;
    S[CSR_WROW8 + w] = u0;
    S[2 * CSR_WROW8 + w] = u0 + u1;
    S[3 * CSR_WROW8 + w] = u0 + u1 + u2;
    tot = u0 + u1 + u2 + u3;
    int n0 = 4 * w;
#pragma unroll
    for (int j = 0; j < 4; ++j)
      if (n0 + j < N) deg[n0 + j] = (int)((tot >> (8 * j)) & 0xffu);
  }
  int s = (int)((tot & 0xffu) + ((tot >> 8) & 0xffu) +
                ((tot >> 16) & 0xffu) + (tot >> 24));
  sh[t] = s;
  __syncthreads();
  for (int off = 128; off >= 1; off >>= 1) {
    if (t < off) sh[t] += sh[t + off];
    __syncthreads();
  }
  if (t == 0) bsum[blockIdx.x] = sh[0];
}

// scan3 with inlined scan2: every block redundantly prefixes the <=64 bsums.
__global__ void k_scan3b(const int* deg, const int* bsum, int nb, int* rowptr,
                         int N) {
  __shared__ int sh[256];
  __shared__ int boff[65];
  int b = blockIdx.x, t = threadIdx.x;
  if (t == 0) {
    int run = 0;
    for (int j = 0; j < nb; ++j) { boff[j] = run; run += bsum[j]; }
    boff[nb] = run;
  }
  int idx0 = b * 1024 + t * 4;
  int v[4], s = 0;
#pragma unroll
  for (int j = 0; j < 4; ++j) {
    int idx = idx0 + j;
    v[j] = (idx < N) ? deg[idx] : 0;
    s += v[j];
  }
  sh[t] = s;
  __syncthreads();
  for (int off = 1; off < 256; off <<= 1) {
    int u = (t >= off) ? sh[t - off] : 0;
    __syncthreads();
    sh[t] += u;
    __syncthreads();
  }
  int run = boff[b] + sh[t] - s;
#pragma unroll
  for (int j = 0; j < 4; ++j) {
    int idx = idx0 + j;
    if (idx < N) {
      rowptr[idx] = run;
      run += v[j];
    }
  }
  if (b == 0 && t == 0) rowptr[N] = boff[nb];
}

// Phase 4: 4 edges/thread; base = G[b][w] + S[b/CHPG][w] (byte-wise, exact).
__global__ void k_fill3(const int* src, const int* dst, const int* rowptr,
                        const unsigned char* rank8, const unsigned int* G,
                        const unsigned int* S, int* col, int E, int N,
                        int chunk) {
  int e0 = (blockIdx.x * 256 + threadIdx.x) * 4;
  if (e0 >= E) return;
  if (e0 + 4 <= E) {
    int4 d4 = *(const int4*)(dst + e0);
    int4 s4 = *(const int4*)(src + e0);
    uchar4 r4 = *(const uchar4*)(rank8 + e0);
    int dd[4] = {d4.x, d4.y, d4.z, d4.w};
    int ss[4] = {s4.x, s4.y, s4.z, s4.w};
    int rr[4] = {r4.x, r4.y, r4.z, r4.w};
#pragma unroll
    for (int j = 0; j < 4; ++j) {
      int d = dd[j], s = ss[j];
      if (d < 0 || d >= N || s < 0 || s >= N) continue;
      int b = (e0 + j) / chunk;
      unsigned int wd = (unsigned int)d >> 2;
      unsigned int base = G[(size_t)b * CSR_WROW8 + wd] +
                          S[(size_t)(b / CHPG) * CSR_WROW8 + wd];
      unsigned int b8 = (base >> ((d & 3) * 8)) & 0xffu;
      col[rowptr[d] + (int)b8 + rr[j]] = s;
    }
  } else {
    for (int e = e0; e < E; ++e) {
      int d = dst[e], s = src[e];
      if (d < 0 || d >= N || s < 0 || s >= N) continue;
      int b = e / chunk;
      unsigned int wd = (unsigned int)d >> 2;
      unsigned int base = G[(size_t)b * CSR_WROW8 + wd] +
                          S[(size_t)(b / CHPG) * CSR_WROW8 + wd];
      unsigned int b8 = (base >> ((d & 3) * 8)) & 0xffu;
      col[rowptr[d] + (int)b8 + (int)rank8[e]] = s;
    }
  }
}

// single-pass fused attention+gather; fp16 in/out. r39 body: prefetch
// pipeline, SINGLE masked FMIX body (no duplication -> no spill).
__global__ void __launch_bounds__(256, 8)
k_gatf(const __half* g, const float* asb, const float* adb,
       const int* rowptr, const int* col, const float* bias,
       const unsigned int* mkey, __half* out, int relu, int N) {
  int w = threadIdx.x >> 6, lane = threadIdx.x & 63;
  int n = blockIdx.x * 4 + w;
  if (n >= N) return;
  int li = lane & 15;   // channel-octet index: channels li*8 .. li*8+7
  int hi = lane >> 4;   // which edge-slot of the 4-slot group
  int h = li >> 2;      // head of this lane's channels
  float adh = adb[(size_t)n * 4 + h];
  float em = key2f(mkey[h]) + adh;      // global upper bound (leaky monotone)
  float mx = em > 0.f ? em : 0.2f * em;
  float a0h = asb[(size_t)n * 4 + h];
  float e0 = a0h + adh;
  float se = e0 > 0.f ? e0 : 0.2f * e0;
  float sw = (hi == 0) ? __expf(se - mx) : 0.f;
  const uint4* g4 = (const uint4*)g;    // row = 16 uint4 (8 halves each)
  float acc0 = 0.f, acc1 = 0.f, acc2 = 0.f, acc3 = 0.f;
  float acc4 = 0.f, acc5 = 0.f, acc6 = 0.f, acc7 = 0.f;
  {
    uint4 gs = g4[(size_t)n * 16 + li];
    FMIX_LO(acc0, gs.x, sw); FMIX_HI(acc1, gs.x, sw);
    FMIX_LO(acc2, gs.y, sw); FMIX_HI(acc3, gs.y, sw);
    FMIX_LO(acc4, gs.z, sw); FMIX_HI(acc5, gs.z, sw);
    FMIX_LO(acc6, gs.w, sw); FMIX_HI(acc7, gs.w, sw);
  }
  float sump = sw;
  int beg = rowptr[n], end = rowptr[n + 1];
  // preload first iteration's col + scores
  int c0 = n, c1 = n, c2 = n, c3 = n;
  float s0, s1, s2, s3;
  {
    int i0 = beg + hi, i1 = beg + 4 + hi, i2 = beg + 8 + hi, i3 = beg + 12 + hi;
    if (i0 < end) c0 = col[i0];
    if (i1 < end) c1 = col[i1];
    if (i2 < end) c2 = col[i2];
    if (i3 < end) c3 = col[i3];
    s0 = asb[(size_t)c0 * 4 + h];
    s1 = asb[(size_t)c1 * 4 + h];
    s2 = asb[(size_t)c2 * 4 + h];
    s3 = asb[(size_t)c3 * 4 + h];
  }
  for (int i = beg; i < end; i += 16) {
    int i0 = i + hi, i1 = i + 4 + hi, i2 = i + 8 + hi, i3 = i + 12 + hi;
    // gathers for current (addresses ready from previous iteration)
    uint4 v0 = g4[(size_t)c0 * 16 + li];
    uint4 v1 = g4[(size_t)c1 * 16 + li];
    uint4 v2 = g4[(size_t)c2 * 16 + li];
    uint4 v3 = g4[(size_t)c3 * 16 + li];
    // prefetch next iteration's col + scores
    int ni = i + 16;
    int nc0 = n, nc1 = n, nc2 = n, nc3 = n;
    if (ni + hi < end) nc0 = col[ni + hi];
    if (ni + 4 + hi < end) nc1 = col[ni + 4 + hi];
    if (ni + 8 + hi < end) nc2 = col[ni + 8 + hi];
    if (ni + 12 + hi < end) nc3 = col[ni + 12 + hi];
    float ns0 = asb[(size_t)nc0 * 4 + h];
    float ns1 = asb[(size_t)nc1 * 4 + h];
    float ns2 = asb[(size_t)nc2 * 4 + h];
    float ns3 = asb[(size_t)nc3 * 4 + h];
    // exp chain with current scores (already in regs)
    float e1 = s0 + adh; e1 = fmaxf(e1, 0.2f * e1);
    float e2 = s1 + adh; e2 = fmaxf(e2, 0.2f * e2);
    float e3 = s2 + adh; e3 = fmaxf(e3, 0.2f * e3);
    float e4 = s3 + adh; e4 = fmaxf(e4, 0.2f * e4);
    float p0 = __expf(e1 - mx), p1 = __expf(e2 - mx);
    float p2 = __expf(e3 - mx), p3 = __expf(e4 - mx);
    if (i0 >= end) p0 = 0.f;
    if (i1 >= end) p1 = 0.f;
    if (i2 >= end) p2 = 0.f;
    if (i3 >= end) p3 = 0.f;
    sump += (p0 + p1) + (p2 + p3);
    FMIX_LO(acc0, v0.x, p0); FMIX_HI(acc1, v0.x, p0);
    FMIX_LO(acc2, v0.y, p0); FMIX_HI(acc3, v0.y, p0);
    FMIX_LO(acc4, v0.z, p0); FMIX_HI(acc5, v0.z, p0);
    FMIX_LO(acc6, v0.w, p0); FMIX_HI(acc7, v0.w, p0);
    FMIX_LO(acc0, v1.x, p1); FMIX_HI(acc1, v1.x, p1);
    FMIX_LO(acc2, v1.y, p1); FMIX_HI(acc3, v1.y, p1);
    FMIX_LO(acc4, v1.z, p1); FMIX_HI(acc5, v1.z, p1);
    FMIX_LO(acc6, v1.w, p1); FMIX_HI(acc7, v1.w, p1);
    FMIX_LO(acc0, v2.x, p2); FMIX_HI(acc1, v2.x, p2);
    FMIX_LO(acc2, v2.y, p2); FMIX_HI(acc3, v2.y, p2);
    FMIX_LO(acc4, v2.z, p2); FMIX_HI(acc5, v2.z, p2);
    FMIX_LO(acc6, v2.w, p2); FMIX_HI(acc7, v2.w, p2);
    FMIX_LO(acc0, v3.x, p3); FMIX_HI(acc1, v3.x, p3);
    FMIX_LO(acc2, v3.y, p3); FMIX_HI(acc3, v3.y, p3);
    FMIX_LO(acc4, v3.z, p3); FMIX_HI(acc5, v3.z, p3);
    FMIX_LO(acc6, v3.w, p3); FMIX_HI(acc7, v3.w, p3);
    c0 = nc0; c1 = nc1; c2 = nc2; c3 = nc3;
    s0 = ns0; s1 = ns1; s2 = ns2; s3 = ns3;
  }
#pragma unroll
  for (int off = 16; off <= 32; off <<= 1) {
    acc0 += __shfl_xor(acc0, off); acc1 += __shfl_xor(acc1, off);
    acc2 += __shfl_xor(acc2, off); acc3 += __shfl_xor(acc3, off);
    acc4 += __shfl_xor(acc4, off); acc5 += __shfl_xor(acc5, off);
    acc6 += __shfl_xor(acc6, off); acc7 += __shfl_xor(acc7, off);
    sump += __shfl_xor(sump, off);
  }
  if (hi == 0) {
    float iv = 1.f / sump;
    const float4* b4 = (const float4*)(bias + li * 8);
    float4 ba = b4[0], bb = b4[1];
    float o0 = acc0 * iv + ba.x, o1 = acc1 * iv + ba.y;
    float o2 = acc2 * iv + ba.z, o3 = acc3 * iv + ba.w;
    float o4 = acc4 * iv + bb.x, o5 = acc5 * iv + bb.y;
    float o6 = acc6 * iv + bb.z, o7 = acc7 * iv + bb.w;
    if (relu) {
      o0 = fmaxf(o0, 0.f); o1 = fmaxf(o1, 0.f);
      o2 = fmaxf(o2, 0.f); o3 = fmaxf(o3, 0.f);
      o4 = fmaxf(o4, 0.f); o5 = fmaxf(o5, 0.f);
      o6 = fmaxf(o6, 0.f); o7 = fmaxf(o7, 0.f);
    }
    H8 hv;
    hv.h[0] = __float2half(o0); hv.h[1] = __float2half(o1);
    hv.h[2] = __float2half(o2); hv.h[3] = __float2half(o3);
    hv.h[4] = __float2half(o4); hv.h[5] = __float2half(o5);
    hv.h[6] = __float2half(o6); hv.h[7] = __float2half(o7);
    *(H8*)(out + (size_t)n * 128 + li * 8) = hv;
  }
}

extern "C" __attribute__((visibility("default"), used)) void kernel_launch(
    void* const* d_in, const int* in_sizes, int n_in, void* d_out, int out_size,
    void* d_ws, size_t ws_size, hipStream_t stream) {
  float* outf = (float*)d_out;
  const int N = in_sizes[0] / 8;
  const int E = in_sizes[1] / 2;

  const float* x = (const float*)d_in[0];
  const int* src = (const int*)d_in[1];
  const int* dst = src + E;
  const float* ce_w1 = (const float*)d_in[2];
  const float* ce_b1 = (const float*)d_in[3];
  const float* ce_w2 = (const float*)d_in[4];
  const float* ce_b2 = (const float*)d_in[5];
  const float* g1_w = (const float*)d_in[6];
  const float* g1_as = (const float*)d_in[7];
  const float* g1_ad = (const float*)d_in[8];
  const float* g1_b = (const float*)d_in[9];
  const float* g2_w = (const float*)d_in[10];
  const float* g2_as = (const float*)d_in[11];
  const float* g2_ad = (const float*)d_in[12];
  const float* g2_b = (const float*)d_in[13];
  const float* ed_w1 = (const float*)d_in[14];
  const float* ed_b1 = (const float*)d_in[15];
  const float* ed_w2 = (const float*)d_in[16];
  const float* ed_b2 = (const float*)d_in[17];
  const float* rp_w1 = (const float*)d_in[18];
  const float* rp_b1 = (const float*)d_in[19];
  const float* rp_w2 = (const float*)d_in[20];
  const float* rp_b2 = (const float*)d_in[21];

  const int nb2 = (N + 1023) / 1024;
  auto al4 = [](size_t v) { return (v + 3) & ~(size_t)3; };
  const size_t wA = 0;
  const size_t wB = wA + (size_t)N * 128;
  const size_t wAs = wB + (size_t)N * 128;
  const size_t wAd = wAs + (size_t)N * 4;
  const size_t wRp = wAd + (size_t)N * 4;
  const size_t wDeg = al4(wRp + (size_t)(N + 1));
  const size_t wCol = al4(wDeg + (size_t)N);
  const size_t wRk = wCol + (size_t)E;
  const size_t wBs = wRk + (size_t)E;  // rank8 uses E bytes of this slot
  const size_t wMk = al4(wBs + (size_t)nb2);
  const size_t wWcH = wMk + 4;
  const size_t wBc = wWcH + 8192;
  const size_t wWpH = al4(wBc + 128);
  const size_t wBp = wWpH + 8192;
  const size_t wG2H = al4(wBp + 128);
  const size_t wS = wG2H + 8192;
  const size_t wEnd = wS + (size_t)CGRP * CSR_WROW8;
  if (ws_size < wEnd * 4) {
    fprintf(stderr, "ATHENA r44: ws too small\n");
    fflush(stderr);
    return;
  }
  if (N > 4 * CSR_NW1 || (size_t)N * 128 < (size_t)CSR_NB * CSR_WROW8 ||
      nb2 > 64) {
    fprintf(stderr, "ATHENA r44: N out of supported range\n");
    fflush(stderr);
    return;
  }
  float* bufA = (float*)d_ws + wA;
  float* bufB = (float*)d_ws + wB;
  float* asb = (float*)d_ws + wAs;
  float* adb = (float*)d_ws + wAd;
  int* rowptr = (int*)d_ws + wRp;
  int* deg = (int*)d_ws + wDeg;
  int* col = (int*)d_ws + wCol;
  unsigned char* rank8 = (unsigned char*)((int*)d_ws + wRk);
  int* bsum = (int*)d_ws + wBs;
  unsigned int* mkey = (unsigned int*)d_ws + wMk;
  __half* WcH = (__half*)((float*)d_ws + wWcH);
  float* bc = (float*)d_ws + wBc;
  __half* WpH = (__half*)((float*)d_ws + wWpH);
  float* bp = (float*)d_ws + wBp;
  __half* G2H = (__half*)((float*)d_ws + wG2H);
  unsigned int* S = (unsigned int*)((float*)d_ws + wS);
  unsigned int* G = (unsigned int*)bufA;  // dead after k_fill3

  const int gb64 = (N + 63) / 64, gb4 = (N + 3) / 4;
  const int eb4 = (E + 1023) / 1024;
  const int chunk = (E + CSR_NB - 1) / CSR_NB;
  const float* nf = (const float*)0;
  float* nfm = (float*)0;
  unsigned int* num = (unsigned int*)0;

  // 1: hist + prep (disjoint blocks; emits swizzled fp16 B tables)
  k_histp<<<CSR_NB + 48, 1024, 0, stream>>>(dst, G, rank8, E, N, chunk,
                                            ed_w1, ed_b1, rp_w1, rp_b1, WcH,
                                            bc, mkey, ce_w2, ce_b2, g1_w, WpH,
                                            bp, g2_w, G2H);
  // 2: colscan-A (4-way chunk split) || GAT1 gemm
  k_csrg<<<CSCAN_NB2 + gb64, 256, 0, stream>>>(G, S, N, WpH, bp, bufB,
                                               g1_as, g1_ad, asb, adb, mkey,
                                               x, ce_w1, ce_b1);
  // 3: colscan-B: group offsets + deg + bsum
  k_cscanb<<<49, 256, 0, stream>>>(S, deg, bsum, N);
  // 4: rowptr (scan2 inlined)
  k_scan3b<<<nb2, 256, 0, stream>>>(deg, bsum, nb2, rowptr, N);
  // 5: fill (last reader of G/S)
  k_fill3<<<eb4, 256, 0, stream>>>(src, dst, rowptr, rank8, G, S, col, E, N,
                                   chunk);
  // 6: GAT1 aggregate: g1=bufB -> h1=bufA (fp16)
  k_gatf<<<gb4, 256, 0, stream>>>((const __half*)bufB, asb, adb, rowptr, col,
                                  g1_b, mkey, (__half*)bufA, 1, N);
  // 7: GAT2 gemm: h1=bufA -> g2=bufB (fp16) + scores
  k_gemm128<<<gb64, 256, 0, stream>>>((const __half*)bufA, G2H, nf, bufB, N,
                                      0, g2_as, g2_ad, asb, adb, mkey,
                                      nf, nf, nf, nf, nfm);
  // 8: GAT2 aggregate: g2=bufB -> h2=bufA (fp16)
  k_gatf<<<gb4, 256, 0, stream>>>((const __half*)bufB, asb, adb, rowptr, col,
                                  g2_b, mkey, (__half*)bufA, 0, N);
  // 9: final hidden gemm + fused output heads
  k_gemm128<<<gb64, 256, 0, stream>>>((const __half*)bufA, WcH, bc, nfm, N, 1,
                                      nf, nf, nfm, nfm, num,
                                      ed_w2, ed_b2, rp_w2, rp_b2, outf);
}

// Round 19
// 338.643 us; speedup vs baseline: 1.0115x; 1.0115x over previous
//
// r45: consolidate at the session-best r43 configuration (340.5us measured).
// r44's colscan 4-way split was a NULL (+2us, within noise): gemm1 — not
// colscan — is csrg's critical path, so the split bought nothing and cost a
// launch (cscanb) + S traffic. Reverted. State: MFMA gemms w/ pre-swizzled
// fp16 B tables (r43), 8-launch graph w/ colscan||gemm1 (r38), fp16
// gatf<->gemm interfaces (r36), r39 gatf (prefetch pipeline, single FMIX
// body), one-pass 8-bit CSR hist w/ byte ranks (r35), vectorized fill (r40).
#include <hip/hip_runtime.h>
#include <hip/hip_fp16.h>
#include <stdio.h>

struct __align__(8) Half4 { __half2 a, b; };
struct __align__(16) H8 { __half h[8]; };

typedef _Float16 f16x8 __attribute__((ext_vector_type(8)));
typedef float f32x4 __attribute__((ext_vector_type(4)));

#define CSR_NB 128       // chunks along edge dim
#define CSR_NW1 12544    // LDS words, full node range (4 nodes/word, 50176B)
#define CSR_WROW8 12544  // words per G row
#define CSCAN_NB 49      // colscan blocks = ceil(12544/256)

// acc += (fp16 half of word) * p, fp32 accumulate (exact fp16->fp32 convert)
#define FMIX_LO(acc, word, p)                                              \
  asm("v_fma_mix_f32 %0, %1, %2, %0 op_sel:[0,0,0] op_sel_hi:[1,0,0]"      \
      : "+v"(acc) : "v"(word), "v"(p))
#define FMIX_HI(acc, word, p)                                              \
  asm("v_fma_mix_f32 %0, %1, %2, %0 op_sel:[1,0,0] op_sel_hi:[1,0,0]"      \
      : "+v"(acc) : "v"(word), "v"(p))

__device__ __forceinline__ unsigned int f2key(float f) {
  unsigned int u = __float_as_uint(f);
  return (u & 0x80000000u) ? ~u : (u | 0x80000000u);
}
__device__ __forceinline__ float key2f(unsigned int k) {
  return __uint_as_float((k & 0x80000000u) ? (k ^ 0x80000000u) : ~k);
}
// swizzled byte offset of element (col, k) in the 32KB B^T LDS image
__device__ __forceinline__ int bswz(int col, int k) {
  return ((col << 8) + (k << 1)) ^ ((col & 7) << 4);
}

// MFMA 128x128 gemm body; BH = pre-swizzled fp16 B^T image (32KB).
__device__ __forceinline__ void gemm_body(
    const __half* Ah, const __half* BH, const float* bias, float* out, int N,
    int relu, const float* att_s, const float* att_d, float* asb, float* adb,
    unsigned int* mkey, const float* encx, const float* encw,
    const float* encb, const float* ew2, const float* eb2, const float* rw2,
    const float* rb2, float* hout, int blk) {
  __shared__ char sbuf[49152] __attribute__((aligned(16)));
  __shared__ __half Wh[1024];
  __shared__ float Wb[128];
  __shared__ unsigned int smax[4];
  char* Btb = sbuf + 16384;
  float* Cs = (float*)sbuf;
  const int t = threadIdx.x, tx = t & 31, ty = t >> 5;
  const int l = t & 63, wv = t >> 6;
  const int row0 = blk * 64;
  if (t < 4) smax[t] = 0u;
  if (encx) {
    for (int i = t; i < 1024; i += 256) Wh[i] = __float2half(encw[i]);
    if (t < 128) Wb[t] = encb[t];
  }
  __syncthreads();
  // ---- stage B^T: straight 16B copies of the pre-swizzled image ----
  {
    const uint4* bh4 = (const uint4*)BH;
    uint4* bt4 = (uint4*)Btb;
    for (int idx = t; idx < 2048; idx += 256) bt4[idx] = bh4[idx];
  }
  if (encx) {
    for (int idx = t; idx < 1024; idx += 256) {
      int r = idx >> 4, u8 = idx & 15, row = row0 + r;
      H8 hv;
      if (row < N) {
        float xv[8];
        *(float4*)(xv) = *(const float4*)(encx + (size_t)row * 8);
        *(float4*)(xv + 4) = *(const float4*)(encx + (size_t)row * 8 + 4);
#pragma unroll
        for (int j = 0; j < 8; ++j) {
          int c = u8 * 8 + j;
          float a = Wb[c];
#pragma unroll
          for (int k = 0; k < 8; ++k)
            a += xv[k] * __half2float(Wh[k * 128 + c]);
          hv.h[j] = __float2half(fmaxf(a, 0.f));
        }
      } else {
#pragma unroll
        for (int j = 0; j < 8; ++j) hv.h[j] = __float2half(0.f);
      }
      int byte = ((r << 8) + (u8 << 4)) ^ ((r & 7) << 4);
      *(H8*)(sbuf + byte) = hv;
    }
  } else {
    for (int idx = t; idx < 1024; idx += 256) {
      int r = idx >> 4, u8 = idx & 15, row = row0 + r;
      H8 hv;
      if (row < N) {
        hv = *(const H8*)(Ah + (size_t)row * 128 + u8 * 8);
      } else {
#pragma unroll
        for (int j = 0; j < 8; ++j) hv.h[j] = __float2half(0.f);
      }
      int byte = ((r << 8) + (u8 << 4)) ^ ((r & 7) << 4);
      *(H8*)(sbuf + byte) = hv;
    }
  }
  __syncthreads();
  f32x4 acc[8];
#pragma unroll
  for (int c = 0; c < 8; ++c) acc[c] = (f32x4){0.f, 0.f, 0.f, 0.f};
  {
    const int lr = l & 15, kb = (l >> 4) * 8;
    const int arow = wv * 16 + lr;
#pragma unroll
    for (int ks = 0; ks < 4; ++ks) {
      int ak = ks * 32 + kb;
      int abyte = ((arow << 8) + (ak << 1)) ^ ((arow & 7) << 4);
      f16x8 af = *(const f16x8*)(sbuf + abyte);
#pragma unroll
      for (int c = 0; c < 8; ++c) {
        int bcol = c * 16 + lr;
        f16x8 bf = *(const f16x8*)(Btb + bswz(bcol, ak));
        acc[c] = __builtin_amdgcn_mfma_f32_16x16x32_f16(af, bf, acc[c], 0, 0, 0);
      }
    }
  }
  __syncthreads();
  {
    const int lr = l & 15, lq = l >> 4;
#pragma unroll
    for (int c = 0; c < 8; ++c)
#pragma unroll
      for (int i = 0; i < 4; ++i)
        Cs[(wv * 16 + lq * 4 + i) * 128 + c * 16 + lr] = acc[c][i];
  }
  __syncthreads();
  float b0 = 0.f, b1 = 0.f, b2 = 0.f, b3 = 0.f;
  const int c0 = tx * 4;
  if (bias) { b0 = bias[c0]; b1 = bias[c0 + 1]; b2 = bias[c0 + 2]; b3 = bias[c0 + 3]; }
  float4 sv = make_float4(0.f, 0.f, 0.f, 0.f), dv = sv;
  if (att_s) {
    sv = *(const float4*)(att_s + c0);
    dv = *(const float4*)(att_d + c0);
  }
  unsigned int kmax = 0u;
#pragma unroll
  for (int i = 0; i < 8; ++i) {
    int row = row0 + ty * 8 + i;
    float4 cv = *(const float4*)(Cs + (ty * 8 + i) * 128 + c0);
    float4 o = make_float4(cv.x + b0, cv.y + b1, cv.z + b2, cv.w + b3);
    if (relu) {
      o.x = fmaxf(o.x, 0.f); o.y = fmaxf(o.y, 0.f);
      o.z = fmaxf(o.z, 0.f); o.w = fmaxf(o.w, 0.f);
    }
    if (att_s) {
      if (row < N) {
        Half4 hv;
        hv.a = __floats2half2_rn(o.x, o.y);
        hv.b = __floats2half2_rn(o.z, o.w);
        *(Half4*)((__half*)out + (size_t)row * 128 + c0) = hv;
      }
      float ps = o.x * sv.x + o.y * sv.y + o.z * sv.z + o.w * sv.w;
      float pd = o.x * dv.x + o.y * dv.y + o.z * dv.z + o.w * dv.w;
#pragma unroll
      for (int off = 4; off >= 1; off >>= 1) {
        ps += __shfl_xor(ps, off);
        pd += __shfl_xor(pd, off);
      }
      if ((tx & 7) == 0 && row < N) {
        int h = tx >> 3;
        asb[(size_t)row * 4 + h] = ps;
        adb[(size_t)row * 4 + h] = pd;
        unsigned int k = f2key(ps);
        kmax = kmax > k ? kmax : k;
      }
    } else if (hout) {
      float pa0 = 0.f, pa1 = 0.f, pa2 = 0.f, pa3 = 0.f, pr = 0.f;
      if (tx < 16) {
        const float* w0 = ew2 + (size_t)c0 * 4;
        pa0 = o.x * w0[0] + o.y * w0[4] + o.z * w0[8] + o.w * w0[12];
        pa1 = o.x * w0[1] + o.y * w0[5] + o.z * w0[9] + o.w * w0[13];
        pa2 = o.x * w0[2] + o.y * w0[6] + o.z * w0[10] + o.w * w0[14];
        pa3 = o.x * w0[3] + o.y * w0[7] + o.z * w0[11] + o.w * w0[15];
      } else {
        const float* wr = rw2 + (c0 - 64);
        pr = o.x * wr[0] + o.y * wr[1] + o.z * wr[2] + o.w * wr[3];
      }
#pragma unroll
      for (int off = 1; off <= 8; off <<= 1) {
        pa0 += __shfl_xor(pa0, off); pa1 += __shfl_xor(pa1, off);
        pa2 += __shfl_xor(pa2, off); pa3 += __shfl_xor(pa3, off);
        pr += __shfl_xor(pr, off);
      }
      if (row < N) {
        if (tx == 0) {
          hout[(size_t)row * 4 + 0] = pa0 + eb2[0];
          hout[(size_t)row * 4 + 1] = pa1 + eb2[1];
          hout[(size_t)row * 4 + 2] = pa2 + eb2[2];
          hout[(size_t)row * 4 + 3] = pa3 + eb2[3];
        }
        if (tx == 16) hout[(size_t)N * 4 + row] = pr + rb2[0];
      }
    } else if (row < N) {
      *(float4*)(out + (size_t)row * 128 + c0) = o;
    }
  }
  if (att_s) {
    if ((tx & 7) == 0 && kmax) atomicMax(&smax[tx >> 3], kmax);
    __syncthreads();
    if (t < 4) atomicMax(&mkey[t], smax[t]);
  }
}

// plain gemm wrapper (GAT2 + final)
__global__ void k_gemm128(const __half* Ah, const __half* BH,
                          const float* bias, float* out, int N, int relu,
                          const float* att_s, const float* att_d, float* asb,
                          float* adb, unsigned int* mkey, const float* ew2,
                          const float* eb2, const float* rw2,
                          const float* rb2, float* hout) {
  gemm_body(Ah, BH, bias, out, N, relu, att_s, att_d, asb, adb, mkey,
            (const float*)0, (const float*)0, (const float*)0, ew2, eb2, rw2,
            rb2, hout, blockIdx.x);
}

// hist (0..127, 1024 thr) + prep: WcH concat+mkey (128..143), wfold->WpH
// (144..159), g2_w->G2H convert (160..175).
__global__ void k_histp(const int* dst, unsigned int* G, unsigned char* rank8,
                        int E, int N, int chunk, const float* ew1,
                        const float* eb1, const float* rw1, const float* rb1,
                        __half* WcH, float* bc, unsigned int* mkey,
                        const float* w2, const float* b2, const float* gw,
                        __half* WpH, float* bp, const float* g2w,
                        __half* G2H) {
  __shared__ unsigned int hist[CSR_NW1];
  const int blk = blockIdx.x, t = threadIdx.x;
  if (blk < CSR_NB) {
    uint4* h4 = (uint4*)hist;
    uint4 z4 = make_uint4(0u, 0u, 0u, 0u);
    for (int i = t; i < CSR_NW1 / 4; i += 1024) h4[i] = z4;
    __syncthreads();
    const int e0 = blk * chunk, e1 = min(E, e0 + chunk);
    for (int e = e0 + t; e < e1; e += 1024) {
      int d = dst[e];
      if (d >= 0 && d < N) {
        int sh = (d & 3) * 8;
        unsigned int old = atomicAdd(&hist[(unsigned int)d >> 2], 1u << sh);
        rank8[e] = (unsigned char)((old >> sh) & 0xffu);
      }
    }
    __syncthreads();
    uint4* row4 = (uint4*)(G + (size_t)blk * CSR_WROW8);
    for (int i = t; i < CSR_NW1 / 4; i += 1024) row4[i] = h4[i];
  } else if (blk < CSR_NB + 16) {
    int i = (blk - CSR_NB) * 1024 + t;
    if (i < 4) mkey[i] = 0u;
    int k = i >> 7, m = i & 127;
    float v = (m < 64) ? ew1[k * 64 + m] : rw1[k * 64 + (m - 64)];
    *(__half*)((char*)WcH + bswz(m, k)) = __float2half(v);
    if (i < 128) bc[i] = (i < 64) ? eb1[i] : rb1[i - 64];
  } else if (blk < CSR_NB + 32) {
    int id = (blk - CSR_NB - 16) * 1024 + t;
    int k = id >> 7, m = id & 127;
    float s = 0.f;
    for (int j = 0; j < 128; ++j) s += w2[k * 128 + j] * gw[j * 128 + m];
    *(__half*)((char*)WpH + bswz(m, k)) = __float2half(s);
    if (id < 128) {
      float s2 = 0.f;
      for (int j = 0; j < 128; ++j) s2 += b2[j] * gw[j * 128 + id];
      bp[id] = s2;
    }
  } else {
    int id = (blk - CSR_NB - 32) * 1024 + t;
    int k = id >> 7, m = id & 127;
    *(__half*)((char*)G2H + bswz(m, k)) = __float2half(g2w[id]);
  }
}

// colscan (blocks 0..48) CONCURRENT with GAT1 gemm (blocks 49..). Disjoint
// memory: colscan G(=bufA)/deg/bsum; gemm1 bufB/asb/adb/mkey.
__global__ void k_csrg(unsigned int* G, int* deg, int* bsum, int N,
                       const __half* BH, const float* bias, float* out,
                       const float* att_s, const float* att_d, float* asb,
                       float* adb, unsigned int* mkey, const float* encx,
                       const float* encw, const float* encb) {
  if (blockIdx.x < CSCAN_NB) {
    __shared__ int sh[256];
    int t = threadIdx.x;
    int w = blockIdx.x * 256 + t;
    unsigned int run = 0u;
    if (w < CSR_WROW8) {
      for (int b = 0; b < CSR_NB; ++b) {
        size_t idx = (size_t)b * CSR_WROW8 + w;
        unsigned int c = G[idx];
        G[idx] = run;
        run += c;
      }
      int n0 = 4 * w;
#pragma unroll
      for (int j = 0; j < 4; ++j)
        if (n0 + j < N) deg[n0 + j] = (int)((run >> (8 * j)) & 0xffu);
    }
    int s = (int)((run & 0xffu) + ((run >> 8) & 0xffu) +
                  ((run >> 16) & 0xffu) + (run >> 24));
    sh[t] = s;
    __syncthreads();
    for (int off = 128; off >= 1; off >>= 1) {
      if (t < off) sh[t] += sh[t + off];
      __syncthreads();
    }
    if (t == 0) bsum[blockIdx.x] = sh[0];
  } else {
    gemm_body((const __half*)0, BH, bias, out, N, 0, att_s, att_d, asb, adb,
              mkey, encx, encw, encb, (const float*)0, (const float*)0,
              (const float*)0, (const float*)0, (float*)0,
              blockIdx.x - CSCAN_NB);
  }
}

// scan3 with inlined scan2: every block redundantly prefixes the <=64 bsums.
__global__ void k_scan3b(const int* deg, const int* bsum, int nb, int* rowptr,
                         int N) {
  __shared__ int sh[256];
  __shared__ int boff[65];
  int b = blockIdx.x, t = threadIdx.x;
  if (t == 0) {
    int run = 0;
    for (int j = 0; j < nb; ++j) { boff[j] = run; run += bsum[j]; }
    boff[nb] = run;
  }
  int idx0 = b * 1024 + t * 4;
  int v[4], s = 0;
#pragma unroll
  for (int j = 0; j < 4; ++j) {
    int idx = idx0 + j;
    v[j] = (idx < N) ? deg[idx] : 0;
    s += v[j];
  }
  sh[t] = s;
  __syncthreads();
  for (int off = 1; off < 256; off <<= 1) {
    int u = (t >= off) ? sh[t - off] : 0;
    __syncthreads();
    sh[t] += u;
    __syncthreads();
  }
  int run = boff[b] + sh[t] - s;
#pragma unroll
  for (int j = 0; j < 4; ++j) {
    int idx = idx0 + j;
    if (idx < N) {
      rowptr[idx] = run;
      run += v[j];
    }
  }
  if (b == 0 && t == 0) rowptr[N] = boff[nb];
}

// Phase 4: 4 edges/thread, int4/uchar4 coalesced loads; scatter unchanged.
__global__ void k_fill3(const int* src, const int* dst, const int* rowptr,
                        const unsigned char* rank8, const unsigned int* G,
                        int* col, int E, int N, int chunk) {
  int e0 = (blockIdx.x * 256 + threadIdx.x) * 4;
  if (e0 >= E) return;
  if (e0 + 4 <= E) {
    int4 d4 = *(const int4*)(dst + e0);
    int4 s4 = *(const int4*)(src + e0);
    uchar4 r4 = *(const uchar4*)(rank8 + e0);
    int dd[4] = {d4.x, d4.y, d4.z, d4.w};
    int ss[4] = {s4.x, s4.y, s4.z, s4.w};
    int rr[4] = {r4.x, r4.y, r4.z, r4.w};
#pragma unroll
    for (int j = 0; j < 4; ++j) {
      int d = dd[j], s = ss[j];
      if (d < 0 || d >= N || s < 0 || s >= N) continue;
      int b = (e0 + j) / chunk;
      unsigned int base = G[(size_t)b * CSR_WROW8 + ((unsigned int)d >> 2)];
      unsigned int b8 = (base >> ((d & 3) * 8)) & 0xffu;
      col[rowptr[d] + (int)b8 + rr[j]] = s;
    }
  } else {
    for (int e = e0; e < E; ++e) {
      int d = dst[e], s = src[e];
      if (d < 0 || d >= N || s < 0 || s >= N) continue;
      int b = e / chunk;
      unsigned int base = G[(size_t)b * CSR_WROW8 + ((unsigned int)d >> 2)];
      unsigned int b8 = (base >> ((d & 3) * 8)) & 0xffu;
      col[rowptr[d] + (int)b8 + (int)rank8[e]] = s;
    }
  }
}

// single-pass fused attention+gather; fp16 in/out. r39 body: prefetch
// pipeline, SINGLE masked FMIX body (no duplication -> no spill).
__global__ void __launch_bounds__(256, 8)
k_gatf(const __half* g, const float* asb, const float* adb,
       const int* rowptr, const int* col, const float* bias,
       const unsigned int* mkey, __half* out, int relu, int N) {
  int w = threadIdx.x >> 6, lane = threadIdx.x & 63;
  int n = blockIdx.x * 4 + w;
  if (n >= N) return;
  int li = lane & 15;   // channel-octet index: channels li*8 .. li*8+7
  int hi = lane >> 4;   // which edge-slot of the 4-slot group
  int h = li >> 2;      // head of this lane's channels
  float adh = adb[(size_t)n * 4 + h];
  float em = key2f(mkey[h]) + adh;      // global upper bound (leaky monotone)
  float mx = em > 0.f ? em : 0.2f * em;
  float a0h = asb[(size_t)n * 4 + h];
  float e0 = a0h + adh;
  float se = e0 > 0.f ? e0 : 0.2f * e0;
  float sw = (hi == 0) ? __expf(se - mx) : 0.f;
  const uint4* g4 = (const uint4*)g;    // row = 16 uint4 (8 halves each)
  float acc0 = 0.f, acc1 = 0.f, acc2 = 0.f, acc3 = 0.f;
  float acc4 = 0.f, acc5 = 0.f, acc6 = 0.f, acc7 = 0.f;
  {
    uint4 gs = g4[(size_t)n * 16 + li];
    FMIX_LO(acc0, gs.x, sw); FMIX_HI(acc1, gs.x, sw);
    FMIX_LO(acc2, gs.y, sw); FMIX_HI(acc3, gs.y, sw);
    FMIX_LO(acc4, gs.z, sw); FMIX_HI(acc5, gs.z, sw);
    FMIX_LO(acc6, gs.w, sw); FMIX_HI(acc7, gs.w, sw);
  }
  float sump = sw;
  int beg = rowptr[n], end = rowptr[n + 1];
  // preload first iteration's col + scores
  int c0 = n, c1 = n, c2 = n, c3 = n;
  float s0, s1, s2, s3;
  {
    int i0 = beg + hi, i1 = beg + 4 + hi, i2 = beg + 8 + hi, i3 = beg + 12 + hi;
    if (i0 < end) c0 = col[i0];
    if (i1 < end) c1 = col[i1];
    if (i2 < end) c2 = col[i2];
    if (i3 < end) c3 = col[i3];
    s0 = asb[(size_t)c0 * 4 + h];
    s1 = asb[(size_t)c1 * 4 + h];
    s2 = asb[(size_t)c2 * 4 + h];
    s3 = asb[(size_t)c3 * 4 + h];
  }
  for (int i = beg; i < end; i += 16) {
    int i0 = i + hi, i1 = i + 4 + hi, i2 = i + 8 + hi, i3 = i + 12 + hi;
    // gathers for current (addresses ready from previous iteration)
    uint4 v0 = g4[(size_t)c0 * 16 + li];
    uint4 v1 = g4[(size_t)c1 * 16 + li];
    uint4 v2 = g4[(size_t)c2 * 16 + li];
    uint4 v3 = g4[(size_t)c3 * 16 + li];
    // prefetch next iteration's col + scores
    int ni = i + 16;
    int nc0 = n, nc1 = n, nc2 = n, nc3 = n;
    if (ni + hi < end) nc0 = col[ni + hi];
    if (ni + 4 + hi < end) nc1 = col[ni + 4 + hi];
    if (ni + 8 + hi < end) nc2 = col[ni + 8 + hi];
    if (ni + 12 + hi < end) nc3 = col[ni + 12 + hi];
    float ns0 = asb[(size_t)nc0 * 4 + h];
    float ns1 = asb[(size_t)nc1 * 4 + h];
    float ns2 = asb[(size_t)nc2 * 4 + h];
    float ns3 = asb[(size_t)nc3 * 4 + h];
    // exp chain with current scores (already in regs)
    float e1 = s0 + adh; e1 = fmaxf(e1, 0.2f * e1);
    float e2 = s1 + adh; e2 = fmaxf(e2, 0.2f * e2);
    float e3 = s2 + adh; e3 = fmaxf(e3, 0.2f * e3);
    float e4 = s3 + adh; e4 = fmaxf(e4, 0.2f * e4);
    float p0 = __expf(e1 - mx), p1 = __expf(e2 - mx);
    float p2 = __expf(e3 - mx), p3 = __expf(e4 - mx);
    if (i0 >= end) p0 = 0.f;
    if (i1 >= end) p1 = 0.f;
    if (i2 >= end) p2 = 0.f;
    if (i3 >= end) p3 = 0.f;
    sump += (p0 + p1) + (p2 + p3);
    FMIX_LO(acc0, v0.x, p0); FMIX_HI(acc1, v0.x, p0);
    FMIX_LO(acc2, v0.y, p0); FMIX_HI(acc3, v0.y, p0);
    FMIX_LO(acc4, v0.z, p0); FMIX_HI(acc5, v0.z, p0);
    FMIX_LO(acc6, v0.w, p0); FMIX_HI(acc7, v0.w, p0);
    FMIX_LO(acc0, v1.x, p1); FMIX_HI(acc1, v1.x, p1);
    FMIX_LO(acc2, v1.y, p1); FMIX_HI(acc3, v1.y, p1);
    FMIX_LO(acc4, v1.z, p1); FMIX_HI(acc5, v1.z, p1);
    FMIX_LO(acc6, v1.w, p1); FMIX_HI(acc7, v1.w, p1);
    FMIX_LO(acc0, v2.x, p2); FMIX_HI(acc1, v2.x, p2);
    FMIX_LO(acc2, v2.y, p2); FMIX_HI(acc3, v2.y, p2);
    FMIX_LO(acc4, v2.z, p2); FMIX_HI(acc5, v2.z, p2);
    FMIX_LO(acc6, v2.w, p2); FMIX_HI(acc7, v2.w, p2);
    FMIX_LO(acc0, v3.x, p3); FMIX_HI(acc1, v3.x, p3);
    FMIX_LO(acc2, v3.y, p3); FMIX_HI(acc3, v3.y, p3);
    FMIX_LO(acc4, v3.z, p3); FMIX_HI(acc5, v3.z, p3);
    FMIX_LO(acc6, v3.w, p3); FMIX_HI(acc7, v3.w, p3);
    c0 = nc0; c1 = nc1; c2 = nc2; c3 = nc3;
    s0 = ns0; s1 = ns1; s2 = ns2; s3 = ns3;
  }
#pragma unroll
  for (int off = 16; off <= 32; off <<= 1) {
    acc0 += __shfl_xor(acc0, off); acc1 += __shfl_xor(acc1, off);
    acc2 += __shfl_xor(acc2, off); acc3 += __shfl_xor(acc3, off);
    acc4 += __shfl_xor(acc4, off); acc5 += __shfl_xor(acc5, off);
    acc6 += __shfl_xor(acc6, off); acc7 += __shfl_xor(acc7, off);
    sump += __shfl_xor(sump, off);
  }
  if (hi == 0) {
    float iv = 1.f / sump;
    const float4* b4 = (const float4*)(bias + li * 8);
    float4 ba = b4[0], bb = b4[1];
    float o0 = acc0 * iv + ba.x, o1 = acc1 * iv + ba.y;
    float o2 = acc2 * iv + ba.z, o3 = acc3 * iv + ba.w;
    float o4 = acc4 * iv + bb.x, o5 = acc5 * iv + bb.y;
    float o6 = acc6 * iv + bb.z, o7 = acc7 * iv + bb.w;
    if (relu) {
      o0 = fmaxf(o0, 0.f); o1 = fmaxf(o1, 0.f);
      o2 = fmaxf(o2, 0.f); o3 = fmaxf(o3, 0.f);
      o4 = fmaxf(o4, 0.f); o5 = fmaxf(o5, 0.f);
      o6 = fmaxf(o6, 0.f); o7 = fmaxf(o7, 0.f);
    }
    H8 hv;
    hv.h[0] = __float2half(o0); hv.h[1] = __float2half(o1);
    hv.h[2] = __float2half(o2); hv.h[3] = __float2half(o3);
    hv.h[4] = __float2half(o4); hv.h[5] = __float2half(o5);
    hv.h[6] = __float2half(o6); hv.h[7] = __float2half(o7);
    *(H8*)(out + (size_t)n * 128 + li * 8) = hv;
  }
}

extern "C" __attribute__((visibility("default"), used)) void kernel_launch(
    void* const* d_in, const int* in_sizes, int n_in, void* d_out, int out_size,
    void* d_ws, size_t ws_size, hipStream_t stream) {
  float* outf = (float*)d_out;
  const int N = in_sizes[0] / 8;
  const int E = in_sizes[1] / 2;

  const float* x = (const float*)d_in[0];
  const int* src = (const int*)d_in[1];
  const int* dst = src + E;
  const float* ce_w1 = (const float*)d_in[2];
  const float* ce_b1 = (const float*)d_in[3];
  const float* ce_w2 = (const float*)d_in[4];
  const float* ce_b2 = (const float*)d_in[5];
  const float* g1_w = (const float*)d_in[6];
  const float* g1_as = (const float*)d_in[7];
  const float* g1_ad = (const float*)d_in[8];
  const float* g1_b = (const float*)d_in[9];
  const float* g2_w = (const float*)d_in[10];
  const float* g2_as = (const float*)d_in[11];
  const float* g2_ad = (const float*)d_in[12];
  const float* g2_b = (const float*)d_in[13];
  const float* ed_w1 = (const float*)d_in[14];
  const float* ed_b1 = (const float*)d_in[15];
  const float* ed_w2 = (const float*)d_in[16];
  const float* ed_b2 = (const float*)d_in[17];
  const float* rp_w1 = (const float*)d_in[18];
  const float* rp_b1 = (const float*)d_in[19];
  const float* rp_w2 = (const float*)d_in[20];
  const float* rp_b2 = (const float*)d_in[21];

  const int nb2 = (N + 1023) / 1024;
  auto al4 = [](size_t v) { return (v + 3) & ~(size_t)3; };
  const size_t wA = 0;
  const size_t wB = wA + (size_t)N * 128;
  const size_t wAs = wB + (size_t)N * 128;
  const size_t wAd = wAs + (size_t)N * 4;
  const size_t wRp = wAd + (size_t)N * 4;
  const size_t wDeg = al4(wRp + (size_t)(N + 1));
  const size_t wCol = al4(wDeg + (size_t)N);
  const size_t wRk = wCol + (size_t)E;
  const size_t wBs = wRk + (size_t)E;  // rank8 uses E bytes of this slot
  const size_t wMk = al4(wBs + (size_t)nb2);
  const size_t wWcH = wMk + 4;
  const size_t wBc = wWcH + 8192;
  const size_t wWpH = al4(wBc + 128);
  const size_t wBp = wWpH + 8192;
  const size_t wG2H = al4(wBp + 128);
  const size_t wEnd = wG2H + 8192;
  if (ws_size < wEnd * 4) {
    fprintf(stderr, "ATHENA r45: ws too small\n");
    fflush(stderr);
    return;
  }
  if (N > 4 * CSR_NW1 || (size_t)N * 128 < (size_t)CSR_NB * CSR_WROW8 ||
      nb2 > 64) {
    fprintf(stderr, "ATHENA r45: N out of supported range\n");
    fflush(stderr);
    return;
  }
  float* bufA = (float*)d_ws + wA;
  float* bufB = (float*)d_ws + wB;
  float* asb = (float*)d_ws + wAs;
  float* adb = (float*)d_ws + wAd;
  int* rowptr = (int*)d_ws + wRp;
  int* deg = (int*)d_ws + wDeg;
  int* col = (int*)d_ws + wCol;
  unsigned char* rank8 = (unsigned char*)((int*)d_ws + wRk);
  int* bsum = (int*)d_ws + wBs;
  unsigned int* mkey = (unsigned int*)d_ws + wMk;
  __half* WcH = (__half*)((float*)d_ws + wWcH);
  float* bc = (float*)d_ws + wBc;
  __half* WpH = (__half*)((float*)d_ws + wWpH);
  float* bp = (float*)d_ws + wBp;
  __half* G2H = (__half*)((float*)d_ws + wG2H);
  unsigned int* G = (unsigned int*)bufA;  // dead after k_fill3

  const int gb64 = (N + 63) / 64, gb4 = (N + 3) / 4;
  const int eb4 = (E + 1023) / 1024;
  const int chunk = (E + CSR_NB - 1) / CSR_NB;
  const float* nf = (const float*)0;
  float* nfm = (float*)0;
  unsigned int* num = (unsigned int*)0;

  // 1: hist + prep (disjoint blocks; emits swizzled fp16 B tables)
  k_histp<<<CSR_NB + 48, 1024, 0, stream>>>(dst, G, rank8, E, N, chunk,
                                            ed_w1, ed_b1, rp_w1, rp_b1, WcH,
                                            bc, mkey, ce_w2, ce_b2, g1_w, WpH,
                                            bp, g2_w, G2H);
  // 2: colscan || GAT1 gemm (g1 -> bufB fp16, G=bufA untouched by gemm)
  k_csrg<<<CSCAN_NB + gb64, 256, 0, stream>>>(G, deg, bsum, N, WpH, bp, bufB,
                                              g1_as, g1_ad, asb, adb, mkey,
                                              x, ce_w1, ce_b1);
  // 3: rowptr (scan2 inlined)
  k_scan3b<<<nb2, 256, 0, stream>>>(deg, bsum, nb2, rowptr, N);
  // 4: fill (last reader of G)
  k_fill3<<<eb4, 256, 0, stream>>>(src, dst, rowptr, rank8, G, col, E, N,
                                   chunk);
  // 5: GAT1 aggregate: g1=bufB -> h1=bufA (fp16)
  k_gatf<<<gb4, 256, 0, stream>>>((const __half*)bufB, asb, adb, rowptr, col,
                                  g1_b, mkey, (__half*)bufA, 1, N);
  // 6: GAT2 gemm: h1=bufA -> g2=bufB (fp16) + scores
  k_gemm128<<<gb64, 256, 0, stream>>>((const __half*)bufA, G2H, nf, bufB, N,
                                      0, g2_as, g2_ad, asb, adb, mkey,
                                      nf, nf, nf, nf, nfm);
  // 7: GAT2 aggregate: g2=bufB -> h2=bufA (fp16)
  k_gatf<<<gb4, 256, 0, stream>>>((const __half*)bufB, asb, adb, rowptr, col,
                                  g2_b, mkey, (__half*)bufA, 0, N);
  // 8: final hidden gemm + fused output heads
  k_gemm128<<<gb64, 256, 0, stream>>>((const __half*)bufA, WcH, bc, nfm, N, 1,
                                      nf, nf, nfm, nfm, num,
                                      ed_w2, ed_b2, rp_w2, rp_b2, outf);
}